// Round 3
// baseline (517.051 us; speedup 1.0000x reference)
//
#include <hip/hip_runtime.h>
#include <hip/hip_bf16.h>
#include <math.h>

typedef short short8 __attribute__((ext_vector_type(8)));
typedef short s4v __attribute__((ext_vector_type(4)));
typedef float f32x4 __attribute__((ext_vector_type(4)));

#define T_TOK 4096
#define D_DIM 1024
#define E_NUM 8
#define F_DIM 4096
#define NSLOT (2 * T_TOK)

#define BM 128
#define BN 128
#define BK 32
#define KSPLIT 2

__device__ __forceinline__ short f2bf(float f) {
  unsigned u = __builtin_bit_cast(unsigned, f);
  u = (u + 0x7FFFu + ((u >> 16) & 1u)) >> 16;
  return (short)u;
}

__device__ __forceinline__ void gload_lds16(unsigned short* lds, const unsigned short* g) {
  __builtin_amdgcn_global_load_lds(
      (const __attribute__((address_space(1))) unsigned int*)g,
      (__attribute__((address_space(3))) unsigned int*)lds, 16, 0, 0);
}

// ---------------- Router: fp64 gates + top-2; also emits x in bf16 ----------------
__global__ __launch_bounds__(64) void router_kernel(
    const float* __restrict__ x, const float* __restrict__ Wg,
    const float* __restrict__ bg,
    int* __restrict__ texp, float* __restrict__ tgate, int* __restrict__ cnt,
    unsigned short* __restrict__ xb) {
  int t = blockIdx.x;
  int lane = threadIdx.x;
  double acc[E_NUM];
#pragma unroll
  for (int e = 0; e < E_NUM; ++e) acc[e] = 0.0;
  const float* xr = x + (size_t)t * D_DIM;
  unsigned short* xbr = xb + (size_t)t * D_DIM;
  for (int d = lane; d < D_DIM; d += 64) {
    float xf = xr[d];
    xbr[d] = (unsigned short)f2bf(xf);
    double xv = (double)xf;
#pragma unroll
    for (int e = 0; e < E_NUM; ++e) acc[e] += xv * (double)Wg[d * E_NUM + e];
  }
#pragma unroll
  for (int off = 32; off > 0; off >>= 1) {
#pragma unroll
    for (int e = 0; e < E_NUM; ++e) acc[e] += __shfl_down(acc[e], off);
  }
  if (lane == 0) {
    double lg[E_NUM];
    double m = -1e300;
#pragma unroll
    for (int e = 0; e < E_NUM; ++e) {
      lg[e] = acc[e] + (double)bg[e];
      m = fmax(m, lg[e]);
    }
    double s = 0.0;
#pragma unroll
    for (int e = 0; e < E_NUM; ++e) { lg[e] = exp(lg[e] - m); s += lg[e]; }
    int e0 = 0; double g0 = lg[0];
#pragma unroll
    for (int e = 1; e < E_NUM; ++e) if (lg[e] > g0) { g0 = lg[e]; e0 = e; }
    int e1 = -1; double g1 = -1.0;
#pragma unroll
    for (int e = 0; e < E_NUM; ++e)
      if (e != e0 && lg[e] > g1) { g1 = lg[e]; e1 = e; }
    texp[2 * t]     = e0;
    texp[2 * t + 1] = e1;
    tgate[2 * t]     = (float)(g0 / s);
    tgate[2 * t + 1] = (float)(g1 / s);
    atomicAdd(&cnt[e0], 1);
    atomicAdd(&cnt[e1], 1);
  }
}

__global__ void offsets_kernel(const int* __restrict__ cnt,
                               int* __restrict__ off, int* __restrict__ cur) {
  if (threadIdx.x == 0 && blockIdx.x == 0) {
    int o = 0;
    for (int e = 0; e < E_NUM; ++e) { off[e] = o; cur[e] = o; o += cnt[e]; }
    off[E_NUM] = o;
  }
}

__global__ __launch_bounds__(256) void assign_kernel(
    const int* __restrict__ texp, const float* __restrict__ tgate,
    int* __restrict__ cur, int* __restrict__ tok_of, float* __restrict__ gate_of) {
  int t = blockIdx.x * 256 + threadIdx.x;
  if (t >= T_TOK) return;
#pragma unroll
  for (int k = 0; k < 2; ++k) {
    int e = texp[2 * t + k];
    int s = atomicAdd(&cur[e], 1);
    tok_of[s] = t;
    gate_of[s] = tgate[2 * t + k];
  }
}

// ---------------- per-expert [R][C] fp32 -> [C][R] bf16 ----------------
__global__ __launch_bounds__(256) void tconv_kernel(
    const float* __restrict__ in, unsigned short* __restrict__ out, int R, int C) {
  __shared__ float tile[64][65];
  int e = blockIdx.z;
  const float* ine = in + (size_t)e * R * C;
  unsigned short* oute = out + (size_t)e * R * C;
  int c0 = blockIdx.x * 64, r0 = blockIdx.y * 64;
  int tid = threadIdx.x;
  int lr = tid >> 4;
  int lc = (tid & 15) * 4;
#pragma unroll
  for (int p = 0; p < 4; ++p) {
    int row = p * 16 + lr;
    float4 v = *(const float4*)&ine[(size_t)(r0 + row) * C + c0 + lc];
    tile[row][lc] = v.x; tile[row][lc + 1] = v.y;
    tile[row][lc + 2] = v.z; tile[row][lc + 3] = v.w;
  }
  __syncthreads();
#pragma unroll
  for (int p = 0; p < 4; ++p) {
    int crow = p * 16 + lr;
    s4v o;
#pragma unroll
    for (int j = 0; j < 4; ++j) o[j] = f2bf(tile[lc + j][crow]);
    *(s4v*)&oute[(size_t)(c0 + crow) * R + r0 + lc] = o;
  }
}

// ---------------- Grouped GEMM1: h = relu(xb @ W1^T + b1), bf16 ----------------
__global__ __launch_bounds__(256) void gemm1_kernel(
    const unsigned short* __restrict__ xb, const unsigned short* __restrict__ w1t,
    const float* __restrict__ b1,
    const int* __restrict__ off, const int* __restrict__ cnt,
    const int* __restrict__ tok_of, unsigned short* __restrict__ h) {
  int e = blockIdx.z;
  int count = cnt[e];
  int ty = blockIdx.y;
  if (ty * BM >= count) return;
  int f0 = blockIdx.x * BN;
  int base = off[e] + ty * BM;

  __shared__ __align__(16) unsigned short As[2][BM * BK];
  __shared__ __align__(16) unsigned short Bs[2][BN * BK];

  int tid = threadIdx.x;
  int lane = tid & 63;
  int wid = tid >> 6;
  int wr = wid >> 1, wc = wid & 1;

  int rowin = lane >> 2;                          // row within 16-row chunk
  int gslot = (lane & 3) ^ ((lane >> 3) & 3);     // pre-swizzled source slot

  const unsigned short* aga[2];
  const unsigned short* bga[2];
  const unsigned short* w1e = w1t + (size_t)e * ((size_t)F_DIM * D_DIM);
#pragma unroll
  for (int r = 0; r < 2; ++r) {
    int row = (r * 4 + wid) * 16 + rowin;
    int idx = ty * BM + row;
    int tok = tok_of[(idx < count) ? (base + row) : off[e]];
    aga[r] = xb + (size_t)tok * D_DIM + gslot * 8;
    bga[r] = w1e + (size_t)(f0 + row) * D_DIM + gslot * 8;
  }

  f32x4 acc[4][4];
#pragma unroll
  for (int m = 0; m < 4; ++m)
#pragma unroll
    for (int n = 0; n < 4; ++n) acc[m][n] = (f32x4){0.f, 0.f, 0.f, 0.f};

  // prologue stage
#pragma unroll
  for (int r = 0; r < 2; ++r) {
    gload_lds16(&As[0][(r * 4 + wid) * 512], aga[r]);
    gload_lds16(&Bs[0][(r * 4 + wid) * 512], bga[r]);
  }
  __syncthreads();

  int rr = lane & 15;
  int pslot16 = (((lane >> 4) ^ ((rr >> 1) & 3)) << 4);  // swizzled 16B slot (byte off)

  const int nk = D_DIM / BK;
  for (int t = 0; t < nk; ++t) {
    int cur = t & 1;
    if (t + 1 < nk) {
      int k0 = (t + 1) * BK;
#pragma unroll
      for (int r = 0; r < 2; ++r) {
        gload_lds16(&As[cur ^ 1][(r * 4 + wid) * 512], aga[r] + k0);
        gload_lds16(&Bs[cur ^ 1][(r * 4 + wid) * 512], bga[r] + k0);
      }
    }
    const char* ab = (const char*)&As[cur][0];
    const char* bb = (const char*)&Bs[cur][0];
    short8 af[4], bf[4];
#pragma unroll
    for (int m = 0; m < 4; ++m)
      af[m] = *(const short8*)(ab + (wr * 64 + m * 16 + rr) * 64 + pslot16);
#pragma unroll
    for (int n = 0; n < 4; ++n)
      bf[n] = *(const short8*)(bb + (wc * 64 + n * 16 + rr) * 64 + pslot16);
#pragma unroll
    for (int m = 0; m < 4; ++m)
#pragma unroll
      for (int n = 0; n < 4; ++n)
        acc[m][n] = __builtin_amdgcn_mfma_f32_16x16x32_bf16(af[m], bf[n], acc[m][n], 0, 0, 0);
    __syncthreads();
  }

  int col = lane & 15, rowb = (lane >> 4) * 4;
#pragma unroll
  for (int m = 0; m < 4; ++m)
#pragma unroll
    for (int i = 0; i < 4; ++i) {
      int rl = wr * 64 + m * 16 + rowb + i;
      if (ty * BM + rl < count) {
        int slot = base + rl;
#pragma unroll
        for (int n = 0; n < 4; ++n) {
          int f = f0 + wc * 64 + n * 16 + col;
          float v = acc[m][n][i] + b1[e * F_DIM + f];
          h[(size_t)slot * F_DIM + f] = (unsigned short)f2bf(fmaxf(v, 0.f));
        }
      }
    }
}

// ---------------- Grouped GEMM2 (split-K): out[tok] += gate*(h @ W2^T + b2) ----------------
__global__ __launch_bounds__(256) void gemm2_kernel(
    const unsigned short* __restrict__ h, const unsigned short* __restrict__ w2t,
    const float* __restrict__ b2,
    const int* __restrict__ off, const int* __restrict__ cnt,
    const int* __restrict__ tok_of, const float* __restrict__ gate_of,
    float* __restrict__ out) {
  int e = blockIdx.z;
  int count = cnt[e];
  int ty = blockIdx.y;
  if (ty * BM >= count) return;
  int dtile = blockIdx.x & ((D_DIM / BN) - 1);
  int kc = blockIdx.x >> 3;                 // D_DIM/BN = 8 tiles -> shift 3
  int d0 = dtile * BN;
  int base = off[e] + ty * BM;
  const int KC = F_DIM / KSPLIT;            // 2048
  const int klo = kc * KC;

  __shared__ __align__(16) unsigned short As[2][BM * BK];
  __shared__ __align__(16) unsigned short Bs[2][BN * BK];

  int tid = threadIdx.x;
  int lane = tid & 63;
  int wid = tid >> 6;
  int wr = wid >> 1, wc = wid & 1;

  int rowin = lane >> 2;
  int gslot = (lane & 3) ^ ((lane >> 3) & 3);

  const unsigned short* aga[2];
  const unsigned short* bga[2];
  const unsigned short* w2e = w2t + (size_t)e * ((size_t)D_DIM * F_DIM);
#pragma unroll
  for (int r = 0; r < 2; ++r) {
    int row = (r * 4 + wid) * 16 + rowin;
    int arow = base + row;
    if (arow > NSLOT - 1) arow = NSLOT - 1;
    aga[r] = h + (size_t)arow * F_DIM + klo + gslot * 8;
    bga[r] = w2e + (size_t)(d0 + row) * F_DIM + klo + gslot * 8;
  }

  f32x4 acc[4][4];
#pragma unroll
  for (int m = 0; m < 4; ++m)
#pragma unroll
    for (int n = 0; n < 4; ++n) acc[m][n] = (f32x4){0.f, 0.f, 0.f, 0.f};

#pragma unroll
  for (int r = 0; r < 2; ++r) {
    gload_lds16(&As[0][(r * 4 + wid) * 512], aga[r]);
    gload_lds16(&Bs[0][(r * 4 + wid) * 512], bga[r]);
  }
  __syncthreads();

  int rr = lane & 15;
  int pslot16 = (((lane >> 4) ^ ((rr >> 1) & 3)) << 4);

  const int nk = KC / BK;                   // 64
  for (int t = 0; t < nk; ++t) {
    int cur = t & 1;
    if (t + 1 < nk) {
      int k0 = (t + 1) * BK;
#pragma unroll
      for (int r = 0; r < 2; ++r) {
        gload_lds16(&As[cur ^ 1][(r * 4 + wid) * 512], aga[r] + k0);
        gload_lds16(&Bs[cur ^ 1][(r * 4 + wid) * 512], bga[r] + k0);
      }
    }
    const char* ab = (const char*)&As[cur][0];
    const char* bb = (const char*)&Bs[cur][0];
    short8 af[4], bf[4];
#pragma unroll
    for (int m = 0; m < 4; ++m)
      af[m] = *(const short8*)(ab + (wr * 64 + m * 16 + rr) * 64 + pslot16);
#pragma unroll
    for (int n = 0; n < 4; ++n)
      bf[n] = *(const short8*)(bb + (wc * 64 + n * 16 + rr) * 64 + pslot16);
#pragma unroll
    for (int m = 0; m < 4; ++m)
#pragma unroll
      for (int n = 0; n < 4; ++n)
        acc[m][n] = __builtin_amdgcn_mfma_f32_16x16x32_bf16(af[m], bf[n], acc[m][n], 0, 0, 0);
    __syncthreads();
  }

  int col = lane & 15, rowb = (lane >> 4) * 4;
#pragma unroll
  for (int m = 0; m < 4; ++m)
#pragma unroll
    for (int i = 0; i < 4; ++i) {
      int rl = wr * 64 + m * 16 + rowb + i;
      if (ty * BM + rl < count) {
        int slot = base + rl;
        int tok = tok_of[slot];
        float g = gate_of[slot];
#pragma unroll
        for (int n = 0; n < 4; ++n) {
          int d = d0 + wc * 64 + n * 16 + col;
          float v = acc[m][n][i] + ((kc == 0) ? b2[e * D_DIM + d] : 0.f);
          atomicAdd(&out[(size_t)tok * D_DIM + d], g * v);
        }
      }
    }
}

extern "C" void kernel_launch(void* const* d_in, const int* in_sizes, int n_in,
                              void* d_out, int out_size, void* d_ws, size_t ws_size,
                              hipStream_t stream) {
  const float* x  = (const float*)d_in[0];
  const float* Wg = (const float*)d_in[1];
  const float* bg = (const float*)d_in[2];
  const float* W1 = (const float*)d_in[3];
  const float* b1 = (const float*)d_in[4];
  const float* W2 = (const float*)d_in[5];
  const float* b2 = (const float*)d_in[6];
  float* out = (float*)d_out;

  char* ws = (char*)d_ws;
  int*   cnt     = (int*)(ws + 0);
  int*   cur     = (int*)(ws + 256);
  int*   off     = (int*)(ws + 512);
  int*   texp    = (int*)(ws + 1024);
  float* tgate   = (float*)(ws + 1024 + NSLOT * 4);
  int*   tok_of  = (int*)(ws + 1024 + NSLOT * 8);
  float* gate_of = (float*)(ws + 1024 + NSLOT * 12);
  size_t o_xb   = 256 * 1024;
  size_t o_wt   = o_xb + (size_t)T_TOK * D_DIM * 2;
  size_t o_h    = o_wt + (size_t)E_NUM * D_DIM * F_DIM * 2;
  unsigned short* xb = (unsigned short*)(ws + o_xb);
  unsigned short* wt = (unsigned short*)(ws + o_wt);
  unsigned short* h  = (unsigned short*)(ws + o_h);

  hipMemsetAsync(ws, 0, 256, stream);
  hipMemsetAsync(d_out, 0, (size_t)out_size * sizeof(float), stream);

  router_kernel<<<T_TOK, 64, 0, stream>>>(x, Wg, bg, texp, tgate, cnt, xb);
  offsets_kernel<<<1, 64, 0, stream>>>(cnt, off, cur);
  assign_kernel<<<(T_TOK + 255) / 256, 256, 0, stream>>>(texp, tgate, cur, tok_of, gate_of);

  // W1 [e][D][F] -> w1t [e][F][D]
  tconv_kernel<<<dim3(F_DIM / 64, D_DIM / 64, E_NUM), 256, 0, stream>>>(W1, wt, D_DIM, F_DIM);
  gemm1_kernel<<<dim3(F_DIM / BN, NSLOT / BM, E_NUM), 256, 0, stream>>>(
      xb, wt, b1, off, cnt, tok_of, h);
  // W2 [e][F][D] -> w2t [e][D][F]
  tconv_kernel<<<dim3(D_DIM / 64, F_DIM / 64, E_NUM), 256, 0, stream>>>(W2, wt, F_DIM, D_DIM);
  gemm2_kernel<<<dim3((D_DIM / BN) * KSPLIT, NSLOT / BM, E_NUM), 256, 0, stream>>>(
      h, wt, b2, off, cnt, tok_of, gate_of, out);
}

// Round 4
// 477.204 us; speedup vs baseline: 1.0835x; 1.0835x over previous
//
#include <hip/hip_runtime.h>
#include <hip/hip_bf16.h>
#include <math.h>

typedef short short8 __attribute__((ext_vector_type(8)));
typedef short s4v __attribute__((ext_vector_type(4)));
typedef float f32x4 __attribute__((ext_vector_type(4)));

#define T_TOK 4096
#define D_DIM 1024
#define E_NUM 8
#define F_DIM 4096
#define NSLOT (2 * T_TOK)

#define BM 128
#define BN 128
#define BK 64
#define NTHREADS 512
#define GRID_ROWS 16   // covers count <= 2048 per expert (mean 1024, sigma ~30)

__device__ __forceinline__ short f2bf(float f) {
  unsigned u = __builtin_bit_cast(unsigned, f);
  u = (u + 0x7FFFu + ((u >> 16) & 1u)) >> 16;
  return (short)u;
}

__device__ __forceinline__ void gload_lds16(unsigned short* lds, const unsigned short* g) {
  __builtin_amdgcn_global_load_lds(
      (const __attribute__((address_space(1))) unsigned int*)g,
      (__attribute__((address_space(3))) unsigned int*)lds, 16, 0, 0);
}

// ---------------- Router: fp64 gates + top-2; also emits x in bf16 ----------------
__global__ __launch_bounds__(64) void router_kernel(
    const float* __restrict__ x, const float* __restrict__ Wg,
    const float* __restrict__ bg,
    int* __restrict__ texp, float* __restrict__ tgate, int* __restrict__ cnt,
    unsigned short* __restrict__ xb) {
  int t = blockIdx.x;
  int lane = threadIdx.x;
  double acc[E_NUM];
#pragma unroll
  for (int e = 0; e < E_NUM; ++e) acc[e] = 0.0;
  const float* xr = x + (size_t)t * D_DIM;
  unsigned short* xbr = xb + (size_t)t * D_DIM;
  for (int d = lane; d < D_DIM; d += 64) {
    float xf = xr[d];
    xbr[d] = (unsigned short)f2bf(xf);
    double xv = (double)xf;
#pragma unroll
    for (int e = 0; e < E_NUM; ++e) acc[e] += xv * (double)Wg[d * E_NUM + e];
  }
#pragma unroll
  for (int off = 32; off > 0; off >>= 1) {
#pragma unroll
    for (int e = 0; e < E_NUM; ++e) acc[e] += __shfl_down(acc[e], off);
  }
  if (lane == 0) {
    double lg[E_NUM];
    double m = -1e300;
#pragma unroll
    for (int e = 0; e < E_NUM; ++e) {
      lg[e] = acc[e] + (double)bg[e];
      m = fmax(m, lg[e]);
    }
    double s = 0.0;
#pragma unroll
    for (int e = 0; e < E_NUM; ++e) { lg[e] = exp(lg[e] - m); s += lg[e]; }
    int e0 = 0; double g0 = lg[0];
#pragma unroll
    for (int e = 1; e < E_NUM; ++e) if (lg[e] > g0) { g0 = lg[e]; e0 = e; }
    int e1 = -1; double g1 = -1.0;
#pragma unroll
    for (int e = 0; e < E_NUM; ++e)
      if (e != e0 && lg[e] > g1) { g1 = lg[e]; e1 = e; }
    texp[2 * t]     = e0;
    texp[2 * t + 1] = e1;
    tgate[2 * t]     = (float)(g0 / s);
    tgate[2 * t + 1] = (float)(g1 / s);
    atomicAdd(&cnt[e0], 1);
    atomicAdd(&cnt[e1], 1);
  }
}

__global__ void offsets_kernel(const int* __restrict__ cnt,
                               int* __restrict__ off, int* __restrict__ cur) {
  if (threadIdx.x == 0 && blockIdx.x == 0) {
    int o = 0;
    for (int e = 0; e < E_NUM; ++e) { off[e] = o; cur[e] = o; o += cnt[e]; }
    off[E_NUM] = o;
  }
}

__global__ __launch_bounds__(256) void assign_kernel(
    const int* __restrict__ texp, const float* __restrict__ tgate,
    int* __restrict__ cur, int* __restrict__ tok_of, float* __restrict__ gate_of) {
  int t = blockIdx.x * 256 + threadIdx.x;
  if (t >= T_TOK) return;
#pragma unroll
  for (int k = 0; k < 2; ++k) {
    int e = texp[2 * t + k];
    int s = atomicAdd(&cur[e], 1);
    tok_of[s] = t;
    gate_of[s] = tgate[2 * t + k];
  }
}

// ---------------- per-expert [R][C] fp32 -> [C][R] bf16 ----------------
__global__ __launch_bounds__(256) void tconv_kernel(
    const float* __restrict__ in, unsigned short* __restrict__ out, int R, int C) {
  __shared__ float tile[64][65];
  int e = blockIdx.z;
  const float* ine = in + (size_t)e * R * C;
  unsigned short* oute = out + (size_t)e * R * C;
  int c0 = blockIdx.x * 64, r0 = blockIdx.y * 64;
  int tid = threadIdx.x;
  int lr = tid >> 4;
  int lc = (tid & 15) * 4;
#pragma unroll
  for (int p = 0; p < 4; ++p) {
    int row = p * 16 + lr;
    float4 v = *(const float4*)&ine[(size_t)(r0 + row) * C + c0 + lc];
    tile[row][lc] = v.x; tile[row][lc + 1] = v.y;
    tile[row][lc + 2] = v.z; tile[row][lc + 3] = v.w;
  }
  __syncthreads();
#pragma unroll
  for (int p = 0; p < 4; ++p) {
    int crow = p * 16 + lr;
    s4v o;
#pragma unroll
    for (int j = 0; j < 4; ++j) o[j] = f2bf(tile[lc + j][crow]);
    *(s4v*)&oute[(size_t)(c0 + crow) * R + r0 + lc] = o;
  }
}

// ============ shared GEMM body pieces (BM=BN=128, BK=64, 512 thr, 8 waves 2x4) ============
// LDS layout per buffer: [row][64 bf16] row-major, 16B granule "slot" 0..7 XOR-swizzled by (row&7).
// global_load_lds dest is linear (pos = i*512+tid granules); global src pre-swizzled.

// ---------------- Grouped GEMM1: h = relu(xb @ W1^T + b1), bf16 ----------------
__global__ __launch_bounds__(NTHREADS) void gemm1_kernel(
    const unsigned short* __restrict__ xb, const unsigned short* __restrict__ w1t,
    const float* __restrict__ b1,
    const int* __restrict__ off, const int* __restrict__ cnt,
    const int* __restrict__ tok_of, unsigned short* __restrict__ h) {
  int e = blockIdx.z;
  int count = cnt[e];
  int ty = blockIdx.y;
  if (ty * BM >= count) return;
  int f0 = blockIdx.x * BN;
  int base = off[e] + ty * BM;

  __shared__ __align__(16) unsigned short As[2][BM * BK];
  __shared__ __align__(16) unsigned short Bs[2][BN * BK];

  int tid = threadIdx.x;
  int lane = tid & 63;
  int wid = tid >> 6;
  int wr = wid >> 2, wc = wid & 3;   // wave-tile 64x32

  // staging: load i covers granule pos = i*512+tid -> (row=pos>>3, slot=tid&7)
  const unsigned short* aga[2];
  const unsigned short* bga[2];
  const unsigned short* w1e = w1t + (size_t)e * ((size_t)F_DIM * D_DIM);
#pragma unroll
  for (int i = 0; i < 2; ++i) {
    int row = (i * NTHREADS + tid) >> 3;
    int sw = (tid & 7) ^ (row & 7);
    int idx = ty * BM + row;
    int tok = tok_of[(idx < count) ? (base + row) : off[e]];
    aga[i] = xb + (size_t)tok * D_DIM + sw * 8;
    bga[i] = w1e + (size_t)(f0 + row) * D_DIM + sw * 8;
  }

  f32x4 acc[4][2];
#pragma unroll
  for (int m = 0; m < 4; ++m)
#pragma unroll
    for (int n = 0; n < 2; ++n) acc[m][n] = (f32x4){0.f, 0.f, 0.f, 0.f};

#define STAGE1(buf, k0) do { \
    gload_lds16(&As[buf][(0 * NTHREADS + tid) * 8], aga[0] + (k0)); \
    gload_lds16(&As[buf][(1 * NTHREADS + tid) * 8], aga[1] + (k0)); \
    gload_lds16(&Bs[buf][(0 * NTHREADS + tid) * 8], bga[0] + (k0)); \
    gload_lds16(&Bs[buf][(1 * NTHREADS + tid) * 8], bga[1] + (k0)); \
  } while (0)

  STAGE1(0, 0);
  asm volatile("s_waitcnt vmcnt(0)" ::: "memory");
  __builtin_amdgcn_s_barrier();

  int rr = lane & 15, hi = lane >> 4;
  const int nk = D_DIM / BK;   // 16
  for (int t = 0; t < nk; ++t) {
    int cur = t & 1;
    if (t + 1 < nk) STAGE1(cur ^ 1, (t + 1) * BK);
    const unsigned short* ab = &As[cur][0];
    const unsigned short* bb = &Bs[cur][0];
#pragma unroll
    for (int kk = 0; kk < 2; ++kk) {
      int so = ((kk * 4 + hi) ^ (rr & 7)) * 8;
      short8 af[4], bf[2];
#pragma unroll
      for (int m = 0; m < 4; ++m)
        af[m] = *(const short8*)(ab + (wr * 64 + m * 16 + rr) * 64 + so);
#pragma unroll
      for (int n = 0; n < 2; ++n)
        bf[n] = *(const short8*)(bb + (wc * 32 + n * 16 + rr) * 64 + so);
#pragma unroll
      for (int m = 0; m < 4; ++m)
#pragma unroll
        for (int n = 0; n < 2; ++n)
          acc[m][n] = __builtin_amdgcn_mfma_f32_16x16x32_bf16(af[m], bf[n], acc[m][n], 0, 0, 0);
    }
    asm volatile("s_waitcnt vmcnt(0)" ::: "memory");
    __builtin_amdgcn_s_barrier();
    __builtin_amdgcn_sched_barrier(0);
  }
#undef STAGE1

  int col = lane & 15, rowq = (lane >> 4) * 4;
#pragma unroll
  for (int m = 0; m < 4; ++m)
#pragma unroll
    for (int i = 0; i < 4; ++i) {
      int rl = wr * 64 + m * 16 + rowq + i;
      if (ty * BM + rl < count) {
        int slot = base + rl;
#pragma unroll
        for (int n = 0; n < 2; ++n) {
          int f = f0 + wc * 32 + n * 16 + col;
          float v = acc[m][n][i] + b1[e * F_DIM + f];
          h[(size_t)slot * F_DIM + f] = (unsigned short)f2bf(fmaxf(v, 0.f));
        }
      }
    }
}

// ---------------- Grouped GEMM2: out[tok] += gate*(h @ W2^T + b2) ----------------
__global__ __launch_bounds__(NTHREADS) void gemm2_kernel(
    const unsigned short* __restrict__ h, const unsigned short* __restrict__ w2t,
    const float* __restrict__ b2,
    const int* __restrict__ off, const int* __restrict__ cnt,
    const int* __restrict__ tok_of, const float* __restrict__ gate_of,
    float* __restrict__ out) {
  int e = blockIdx.z;
  int count = cnt[e];
  int ty = blockIdx.y;
  if (ty * BM >= count) return;
  int d0 = blockIdx.x * BN;
  int base = off[e] + ty * BM;

  __shared__ __align__(16) unsigned short As[2][BM * BK];
  __shared__ __align__(16) unsigned short Bs[2][BN * BK];

  int tid = threadIdx.x;
  int lane = tid & 63;
  int wid = tid >> 6;
  int wr = wid >> 2, wc = wid & 3;

  const unsigned short* aga[2];
  const unsigned short* bga[2];
  const unsigned short* w2e = w2t + (size_t)e * ((size_t)D_DIM * F_DIM);
#pragma unroll
  for (int i = 0; i < 2; ++i) {
    int row = (i * NTHREADS + tid) >> 3;
    int sw = (tid & 7) ^ (row & 7);
    int arow = base + row;
    if (arow > NSLOT - 1) arow = NSLOT - 1;
    aga[i] = h + (size_t)arow * F_DIM + sw * 8;
    bga[i] = w2e + (size_t)(d0 + row) * F_DIM + sw * 8;
  }

  f32x4 acc[4][2];
#pragma unroll
  for (int m = 0; m < 4; ++m)
#pragma unroll
    for (int n = 0; n < 2; ++n) acc[m][n] = (f32x4){0.f, 0.f, 0.f, 0.f};

#define STAGE2(buf, k0) do { \
    gload_lds16(&As[buf][(0 * NTHREADS + tid) * 8], aga[0] + (k0)); \
    gload_lds16(&As[buf][(1 * NTHREADS + tid) * 8], aga[1] + (k0)); \
    gload_lds16(&Bs[buf][(0 * NTHREADS + tid) * 8], bga[0] + (k0)); \
    gload_lds16(&Bs[buf][(1 * NTHREADS + tid) * 8], bga[1] + (k0)); \
  } while (0)

  STAGE2(0, 0);
  asm volatile("s_waitcnt vmcnt(0)" ::: "memory");
  __builtin_amdgcn_s_barrier();

  int rr = lane & 15, hi = lane >> 4;
  const int nk = F_DIM / BK;   // 64
  for (int t = 0; t < nk; ++t) {
    int cur = t & 1;
    if (t + 1 < nk) STAGE2(cur ^ 1, (t + 1) * BK);
    const unsigned short* ab = &As[cur][0];
    const unsigned short* bb = &Bs[cur][0];
#pragma unroll
    for (int kk = 0; kk < 2; ++kk) {
      int so = ((kk * 4 + hi) ^ (rr & 7)) * 8;
      short8 af[4], bf[2];
#pragma unroll
      for (int m = 0; m < 4; ++m)
        af[m] = *(const short8*)(ab + (wr * 64 + m * 16 + rr) * 64 + so);
#pragma unroll
      for (int n = 0; n < 2; ++n)
        bf[n] = *(const short8*)(bb + (wc * 32 + n * 16 + rr) * 64 + so);
#pragma unroll
      for (int m = 0; m < 4; ++m)
#pragma unroll
        for (int n = 0; n < 2; ++n)
          acc[m][n] = __builtin_amdgcn_mfma_f32_16x16x32_bf16(af[m], bf[n], acc[m][n], 0, 0, 0);
    }
    asm volatile("s_waitcnt vmcnt(0)" ::: "memory");
    __builtin_amdgcn_s_barrier();
    __builtin_amdgcn_sched_barrier(0);
  }
#undef STAGE2

  int col = lane & 15, rowq = (lane >> 4) * 4;
#pragma unroll
  for (int m = 0; m < 4; ++m)
#pragma unroll
    for (int i = 0; i < 4; ++i) {
      int rl = wr * 64 + m * 16 + rowq + i;
      if (ty * BM + rl < count) {
        int slot = base + rl;
        int tok = tok_of[slot];
        float g = gate_of[slot];
#pragma unroll
        for (int n = 0; n < 2; ++n) {
          int d = d0 + wc * 32 + n * 16 + col;
          float v = acc[m][n][i] + b2[e * D_DIM + d];
          atomicAdd(&out[(size_t)tok * D_DIM + d], g * v);
        }
      }
    }
}

extern "C" void kernel_launch(void* const* d_in, const int* in_sizes, int n_in,
                              void* d_out, int out_size, void* d_ws, size_t ws_size,
                              hipStream_t stream) {
  const float* x  = (const float*)d_in[0];
  const float* Wg = (const float*)d_in[1];
  const float* bg = (const float*)d_in[2];
  const float* W1 = (const float*)d_in[3];
  const float* b1 = (const float*)d_in[4];
  const float* W2 = (const float*)d_in[5];
  const float* b2 = (const float*)d_in[6];
  float* out = (float*)d_out;

  char* ws = (char*)d_ws;
  int*   cnt     = (int*)(ws + 0);
  int*   cur     = (int*)(ws + 256);
  int*   off     = (int*)(ws + 512);
  int*   texp    = (int*)(ws + 1024);
  float* tgate   = (float*)(ws + 1024 + NSLOT * 4);
  int*   tok_of  = (int*)(ws + 1024 + NSLOT * 8);
  float* gate_of = (float*)(ws + 1024 + NSLOT * 12);
  size_t o_xb   = 256 * 1024;
  size_t o_wt   = o_xb + (size_t)T_TOK * D_DIM * 2;                 // +8 MB
  size_t o_h    = o_wt + (size_t)E_NUM * D_DIM * F_DIM * 2;         // +64 MB
  unsigned short* xb = (unsigned short*)(ws + o_xb);
  unsigned short* wt = (unsigned short*)(ws + o_wt);
  unsigned short* h  = (unsigned short*)(ws + o_h);

  hipMemsetAsync(ws, 0, 256, stream);
  hipMemsetAsync(d_out, 0, (size_t)out_size * sizeof(float), stream);

  router_kernel<<<T_TOK, 64, 0, stream>>>(x, Wg, bg, texp, tgate, cnt, xb);
  offsets_kernel<<<1, 64, 0, stream>>>(cnt, off, cur);
  assign_kernel<<<(T_TOK + 255) / 256, 256, 0, stream>>>(texp, tgate, cur, tok_of, gate_of);

  // W1 [e][D][F] -> w1t [e][F][D]
  tconv_kernel<<<dim3(F_DIM / 64, D_DIM / 64, E_NUM), 256, 0, stream>>>(W1, wt, D_DIM, F_DIM);
  gemm1_kernel<<<dim3(F_DIM / BN, GRID_ROWS, E_NUM), NTHREADS, 0, stream>>>(
      xb, wt, b1, off, cnt, tok_of, h);
  // W2 [e][F][D] -> w2t [e][D][F]
  tconv_kernel<<<dim3(D_DIM / 64, F_DIM / 64, E_NUM), 256, 0, stream>>>(W2, wt, F_DIM, D_DIM);
  gemm2_kernel<<<dim3(D_DIM / BN, GRID_ROWS, E_NUM), NTHREADS, 0, stream>>>(
      h, wt, b2, off, cnt, tok_of, gate_of, out);
}